// Round 8
// baseline (396.392 us; speedup 1.0000x reference)
//
#include <hip/hip_runtime.h>

#define N_NODES 50000
#define N_EDGES 1600000
#define NPB     16
#define NBINS   (N_NODES / NPB)   // 3125 bins = node-blocks
#define NCHAIN  16    // overflow/fat sub-chains per node: chain = e & 15
#define KSTR    168   // A-tile k-stride in shorts (160 + 8 pad: breaks bank conflict on A-frag ds_read_b128)
#define EPSV    1e-8f

typedef float f32x4 __attribute__((ext_vector_type(4)));
typedef short s16x8 __attribute__((ext_vector_type(8)));

// 4-aligned 16B chunk (frames rows are 36B / pay slots 48B, only 4B-aligned)
struct f4u { float a, b, c, d; };

__device__ __forceinline__ float sigmoidf_(float x) { return 1.0f / (1.0f + __expf(-x)); }
// f32 -> bf16 bits, round-to-nearest-even
__device__ __forceinline__ short f2bf(float x) {
    unsigned u = __float_as_uint(x);
    unsigned r = (u + 0x7FFFu + ((u >> 16) & 1u)) >> 16;
    return (short)r;
}
__device__ __forceinline__ float bf2f(short h) {
    return __uint_as_float(((unsigned)(unsigned short)h) << 16);
}

// ---------------------------------------------------------------------------
// Init kernel: counters/chains init AND Dekker-split W_so into TRANSPOSED
// bf16 hi/lo WT[o][k] (k-contiguous B-frags), k>=153 zeroed.
// mode 3 (bin): p0=bincnt[3125]=0, p1=head2[50K*16]=-1
// mode 1/0 (fat/thin): p0=head[50K*16]=-1
// ---------------------------------------------------------------------------
__global__ __launch_bounds__(256) void init_kernel(
    const float* __restrict__ W_so, short* __restrict__ WThi, short* __restrict__ WTlo,
    int* __restrict__ p0, int* __restrict__ p1, int mode) {
    int i = blockIdx.x * 256 + threadIdx.x;
    if (i < 128 * 160) {               // i = o*160 + k
        int o = i / 160, k = i - o * 160;
        float w = (k < 153) ? W_so[k * 128 + o] : 0.0f;
        short hh = f2bf(w);
        WThi[i] = hh;
        WTlo[i] = f2bf(w - bf2f(hh));
    }
    if (mode == 3) {
        if (i < NBINS) p0[i] = 0;
        if (i < N_NODES * NCHAIN) p1[i] = -1;
    } else {
        if (i < N_NODES * NCHAIN) p0[i] = -1;
    }
}

// ---------------------------------------------------------------------------
// Kernel 1 (BIN): radix-partition the edges into 3125 node-block bins.
// Per edge: 1 atomicAdd (random, minimal fabric) + coalesced frame read +
// 40B append {f0..f8, nid} into the bin's tail. 3125 tail lines = 200KB
// (cache-resident) filling every ~100-200ns -> lines complete while resident
// -> full-line HBM writes (r7's per-node CSR had 50K tails @ 3.6us fill gap
// -> evicted partial, 2x amplification). Overflow (slot>=cap, ~0 edges at
// cap 639) -> 16-way per-node chains.
// ---------------------------------------------------------------------------
__global__ __launch_bounds__(256) void bucket_bin_kernel(
    const int* __restrict__ row,
    const float* __restrict__ frames,
    int* __restrict__ bincnt,
    int* __restrict__ head2,
    int* __restrict__ nxt,
    float* __restrict__ pay,
    int cap) {
    int e = blockIdx.x * 256 + threadIdx.x;
    if (e >= N_EDGES) return;
    int r = row[e];
    int b = r >> 4;
    int slot = atomicAdd(&bincnt[b], 1);
    const float* f = frames + (size_t)e * 9;
    f4u x = ((const f4u*)f)[0];
    f4u y = ((const f4u*)f)[1];
    float z8 = f[8];
    if (slot < cap) {
        float* dst = pay + ((size_t)b * cap + slot) * 12;
        ((f4u*)dst)[0] = x;
        ((f4u*)dst)[1] = y;
        dst[8] = z8;
        ((int*)dst)[9] = r & (NPB - 1);   // node-local id
        // words 10,11 unwritten (pad)
    } else {
        int prev = atomicExch(&head2[r * NCHAIN + (e & (NCHAIN - 1))], e);
        nxt[e] = prev;
    }
}

// Kernel 1 (FAT fallback): chain pointer rides in the same 64B line as the
// frame -> one random line per node-side hop. (r6-proven)
__global__ __launch_bounds__(256) void bucket_fat_kernel(
    const int* __restrict__ row,
    const float* __restrict__ frames,
    int* __restrict__ head,
    float* __restrict__ pay) {
    int e = blockIdx.x * 256 + threadIdx.x;
    if (e >= N_EDGES) return;
    int r = row[e];
    int prev = atomicExch(&head[r * NCHAIN + (e & (NCHAIN - 1))], e);
    const float* f = frames + (size_t)e * 9;
    f4u x = ((const f4u*)f)[0];
    f4u y = ((const f4u*)f)[1];
    float z8 = f[8];
    float4* dst = (float4*)(pay + (size_t)e * 16);
    dst[0] = make_float4(x.a, x.b, x.c, x.d);
    dst[1] = make_float4(y.a, y.b, y.c, y.d);
    dst[2] = make_float4(z8, __int_as_float(prev), 0.0f, 0.0f);
}

// Thin fallback (tiny ws): classic separate-nxt bucketing.
__global__ __launch_bounds__(256) void bucket_thin_kernel(
    const int* __restrict__ row,
    int* __restrict__ head,
    int* __restrict__ nxt) {
    int e = blockIdx.x * 256 + threadIdx.x;
    if (e >= N_EDGES) return;
    int r = row[e];
    int prev = atomicExch(&head[r * NCHAIN + (e & (NCHAIN - 1))], e);
    nxt[e] = prev;
}

// ---------------------------------------------------------------------------
// Kernel 2 (BIN): block b owns bin b = nodes [16b,16b+16). Gather = fully
// coalesced contiguous slot read (no chains, no hops); 16-node demux via
// LDS atomicAdd into FsumL[16][10] (deg rides as the +1 lane). Overflow
// chains walked as before (rare). Downstream algebra identical to r6.
// ---------------------------------------------------------------------------
__global__ __launch_bounds__(256) void node_bin_kernel(
    const float* __restrict__ s,
    const float* __restrict__ v,
    const float* __restrict__ pay,
    const float* __restrict__ frames_raw,
    const float* __restrict__ W_vd,
    const float* __restrict__ W_vdf,
    const short* __restrict__ WThi,
    const short* __restrict__ WTlo,
    const float* __restrict__ b_so,
    const float* __restrict__ W_vu,
    const float* __restrict__ W_vosf,
    const float* __restrict__ b_vosf,
    const float* __restrict__ W_vuf,
    const int* __restrict__ bincnt,
    const int* __restrict__ head2,
    const int* __restrict__ nxt,
    int cap,
    float* __restrict__ out0,
    float* __restrict__ out1)
{
    __shared__ __align__(16) short AL[2][NPB][KSTR];  // 10.5 KB; sigL overlays after K-loop
    __shared__ float vL[NPB][48];
    __shared__ float vhL[NPB][3][16];
    __shared__ float FbarL[NPB][9];
    __shared__ float gateL[NPB][12];
    __shared__ float FsumL[NPB][10];

    float (*sigL)[128] = (float (*)[128])&AL[0][0][0];

    const int t = threadIdx.x;
    const int base = blockIdx.x * NPB;
    const int nn = t >> 4, h = t & 15;
    const int n = base + nn;

    // ---- phase 0a: zero FsumL, stage v, s(->bf16 hi/lo) ----
    if (t < NPB * 10) ((float*)FsumL)[t] = 0.0f;
#pragma unroll
    for (int r = 0; r < 3; r++) vL[nn][h * 3 + r] = v[(size_t)n * 48 + h * 3 + r];
    {
        const float4* sp4 = (const float4*)(s + (size_t)n * 128 + h * 8);
        float4 s0 = sp4[0], s1 = sp4[1];
        float sv[8] = {s0.x, s0.y, s0.z, s0.w, s1.x, s1.y, s1.z, s1.w};
        s16x8 shi, slo;
#pragma unroll
        for (int j = 0; j < 8; j++) {
            short hh = f2bf(sv[j]);
            shi[j] = hh;
            slo[j] = f2bf(sv[j] - bf2f(hh));
        }
        *(s16x8*)&AL[0][nn][h * 8] = shi;
        *(s16x8*)&AL[1][nn][h * 8] = slo;
    }
    __syncthreads();

    // ---- phase 0b: coalesced bin gather + LDS-atomic demux ----
    {
        int cn = bincnt[blockIdx.x];
        int lim = cn < cap ? cn : cap;
        for (int slot = t; slot < lim; slot += 256) {
            const float* pp = pay + ((size_t)blockIdx.x * cap + slot) * 12;
            f4u c0 = ((const f4u*)pp)[0];
            f4u c1 = ((const f4u*)pp)[1];
            float f8 = pp[8];
            int nid = ((const int*)pp)[9];
            float* Fs = FsumL[nid];
            atomicAdd(&Fs[0], c0.a); atomicAdd(&Fs[1], c0.b);
            atomicAdd(&Fs[2], c0.c); atomicAdd(&Fs[3], c0.d);
            atomicAdd(&Fs[4], c1.a); atomicAdd(&Fs[5], c1.b);
            atomicAdd(&Fs[6], c1.c); atomicAdd(&Fs[7], c1.d);
            atomicAdd(&Fs[8], f8);   atomicAdd(&Fs[9], 1.0f);
        }
        // overflow chains (rare): 16 lanes per node
        int e2 = head2[(size_t)n * NCHAIN + h];
        while (e2 >= 0) {
            int en = nxt[e2];
            const float* f = frames_raw + (size_t)e2 * 9;
            f4u x = ((const f4u*)f)[0];
            f4u y = ((const f4u*)f)[1];
            float z8 = f[8];
            float* Fs = FsumL[nn];
            atomicAdd(&Fs[0], x.a); atomicAdd(&Fs[1], x.b);
            atomicAdd(&Fs[2], x.c); atomicAdd(&Fs[3], x.d);
            atomicAdd(&Fs[4], y.a); atomicAdd(&Fs[5], y.b);
            atomicAdd(&Fs[6], y.c); atomicAdd(&Fs[7], y.d);
            atomicAdd(&Fs[8], z8);  atomicAdd(&Fs[9], 1.0f);
            e2 = en;
        }
    }
    __syncthreads();

    // ---- phase 1 (fused): vh, vnorm(->A[128+h]), sh(->A[144..152]) ----
    {
        float fs[10];
#pragma unroll
        for (int k = 0; k < 10; k++) fs[k] = FsumL[nn][k];
        float invdeg = 1.0f / fmaxf(fs[9], 1.0f);
        if (h < 9) FbarL[nn][h] = fs[h] * invdeg;   // for phase 3

        float vh0 = 0.f, vh1 = 0.f, vh2 = 0.f;
#pragma unroll
        for (int i = 0; i < 16; i++) {
            float w = W_vd[i * 16 + h];
            vh0 += vL[nn][i * 3 + 0] * w;
            vh1 += vL[nn][i * 3 + 1] * w;
            vh2 += vL[nn][i * 3 + 2] * w;
        }
        vhL[nn][0][h] = vh0; vhL[nn][1][h] = vh1; vhL[nn][2][h] = vh2;
        float vn = sqrtf(vh0 * vh0 + vh1 * vh1 + vh2 * vh2 + EPSV);
        short hh = f2bf(vn);
        AL[0][nn][128 + h] = hh;
        AL[1][nn][128 + h] = f2bf(vn - bf2f(hh));
        if (h < 9) {
            const int c = h / 3, i = h % 3;
            float a = 0.f;
#pragma unroll
            for (int j = 0; j < 3; j++) {
                float vd = 0.f;
#pragma unroll
                for (int ii = 0; ii < 16; ii++) vd += vL[nn][ii * 3 + j] * W_vdf[ii * 3 + c];
                a += (fs[i * 3 + j] * invdeg) * vd;
            }
            short hs = f2bf(a);
            AL[0][nn][144 + h] = hs;
            AL[1][nn][144 + h] = f2bf(a - bf2f(hs));
        } else {
            AL[0][nn][144 + h] = 0;
            AL[1][nn][144 + h] = 0;
        }
    }
    __syncthreads();

    // ---- phase 2: C[16x128] = merged[16x160] @ W_so via split-bf16 MFMA ----
    {
        const int w = t >> 6;
        const int lane = t & 63;
        const int quad = lane >> 4;
        const int col = lane & 15;
        const int o0 = w * 32 + col, o1 = o0 + 16;
        f32x4 acc0 = (f32x4){0.f, 0.f, 0.f, 0.f};
        f32x4 acc1 = (f32x4){0.f, 0.f, 0.f, 0.f};
#pragma unroll
        for (int kk = 0; kk < 5; kk++) {
            const int krow = kk * 32 + quad * 8;
            s16x8 ahi = *(const s16x8*)&AL[0][col][krow];
            s16x8 alo = *(const s16x8*)&AL[1][col][krow];
            s16x8 b0h = *(const s16x8*)&WThi[o0 * 160 + krow];
            s16x8 b0l = *(const s16x8*)&WTlo[o0 * 160 + krow];
            s16x8 b1h = *(const s16x8*)&WThi[o1 * 160 + krow];
            s16x8 b1l = *(const s16x8*)&WTlo[o1 * 160 + krow];
            acc0 = __builtin_amdgcn_mfma_f32_16x16x32_bf16(ahi, b0h, acc0, 0, 0, 0);
            acc0 = __builtin_amdgcn_mfma_f32_16x16x32_bf16(ahi, b0l, acc0, 0, 0, 0);
            acc0 = __builtin_amdgcn_mfma_f32_16x16x32_bf16(alo, b0h, acc0, 0, 0, 0);
            acc1 = __builtin_amdgcn_mfma_f32_16x16x32_bf16(ahi, b1h, acc1, 0, 0, 0);
            acc1 = __builtin_amdgcn_mfma_f32_16x16x32_bf16(ahi, b1l, acc1, 0, 0, 0);
            acc1 = __builtin_amdgcn_mfma_f32_16x16x32_bf16(alo, b1h, acc1, 0, 0, 0);
        }
        __syncthreads();
        {
            float b0 = b_so[o0], b1 = b_so[o1];
#pragma unroll
            for (int r = 0; r < 4; r++) {
                int nl = quad * 4 + r;
                float v0 = acc0[r] + b0;
                float v1 = acc1[r] + b1;
                out0[(size_t)(base + nl) * 128 + o0] = fmaxf(v0, 0.0f);
                out0[(size_t)(base + nl) * 128 + o1] = fmaxf(v1, 0.0f);
                sigL[nl][o0] = sigmoidf_(v0);
                sigL[nl][o1] = sigmoidf_(v1);
            }
        }
    }
    __syncthreads();

    // ---- gate = sigmoid(sr) @ W_vosf + b_vosf ----
    {
        const float* sp = &sigL[nn][h * 8];
        float4 s0 = *(const float4*)sp;
        float4 s1 = *(const float4*)(sp + 4);
        float sv[8] = {s0.x, s0.y, s0.z, s0.w, s1.x, s1.y, s1.z, s1.w};
        float p[9];
#pragma unroll
        for (int k = 0; k < 9; k++) p[k] = 0.f;
#pragma unroll
        for (int i = 0; i < 8; i++) {
            int o = h * 8 + i;
#pragma unroll
            for (int k = 0; k < 9; k++) p[k] += sv[i] * W_vosf[o * 9 + k];
        }
#pragma unroll
        for (int m = 1; m < 16; m <<= 1) {
#pragma unroll
            for (int k = 0; k < 9; k++) p[k] += __shfl_xor(p[k], m);
        }
        if (h < 9) gateL[nn][h] = p[h] + b_vosf[h];
    }
    __syncthreads();

    // ---- phase 3: vector path ----
    {
        int o = h;
        float gv[9];
#pragma unroll
        for (int i = 0; i < 3; i++)
#pragma unroll
            for (int kk = 0; kk < 3; kk++) {
                float a = 0.f;
#pragma unroll
                for (int j = 0; j < 3; j++) a += gateL[nn][j * 3 + i] * FbarL[nn][j * 3 + kk];
                gv[i * 3 + kk] = a;
            }
        float gvr[3];
#pragma unroll
        for (int kk = 0; kk < 3; kk++) {
            float a = 0.f;
#pragma unroll
            for (int i = 0; i < 3; i++) a += gv[i * 3 + kk] * W_vuf[i * 16 + o];
            gvr[kk] = a;
        }
        float gn2 = sqrtf(gvr[0] * gvr[0] + gvr[1] * gvr[1] + gvr[2] * gvr[2] + EPSV);
        float sg = sigmoidf_(gn2);
#pragma unroll
        for (int c = 0; c < 3; c++) {
            float a = 0.f;
#pragma unroll
            for (int h2 = 0; h2 < 16; h2++) a += vhL[nn][c][h2] * W_vu[h2 * 16 + o];
            out1[(size_t)n * 48 + o * 3 + c] = a * sg;
        }
    }
}

// ---------------------------------------------------------------------------
// Fallback node kernel (r6-proven): MODE 1 fat chains, MODE 0 thin.
// ---------------------------------------------------------------------------
template<int MODE>
__global__ __launch_bounds__(256) void node_kernel(
    const float* __restrict__ s,
    const float* __restrict__ v,
    const float* __restrict__ fr,      // M1: pay64; M0: frames
    const float* __restrict__ W_vd,
    const float* __restrict__ W_vdf,
    const short* __restrict__ WThi,
    const short* __restrict__ WTlo,
    const float* __restrict__ b_so,
    const float* __restrict__ W_vu,
    const float* __restrict__ W_vosf,
    const float* __restrict__ b_vosf,
    const float* __restrict__ W_vuf,
    const int* __restrict__ head,
    const int* __restrict__ nxt,       // M0 only
    float* __restrict__ out0,
    float* __restrict__ out1)
{
    __shared__ __align__(16) short AL[2][NPB][KSTR];
    __shared__ float vL[NPB][48];
    __shared__ float vhL[NPB][3][16];
    __shared__ float FbarL[NPB][9];
    __shared__ float gateL[NPB][12];

    float (*sigL)[128] = (float (*)[128])&AL[0][0][0];

    const int t = threadIdx.x;
    const int base = blockIdx.x * NPB;
    const int nn = t >> 4, h = t & 15;
    const int n = base + nn;

    int e = head[(size_t)n * NCHAIN + h];

#pragma unroll
    for (int r = 0; r < 3; r++) vL[nn][h * 3 + r] = v[(size_t)n * 48 + h * 3 + r];
    {
        const float4* sp4 = (const float4*)(s + (size_t)n * 128 + h * 8);
        float4 s0 = sp4[0], s1 = sp4[1];
        float sv[8] = {s0.x, s0.y, s0.z, s0.w, s1.x, s1.y, s1.z, s1.w};
        s16x8 shi, slo;
#pragma unroll
        for (int j = 0; j < 8; j++) {
            short hh = f2bf(sv[j]);
            shi[j] = hh;
            slo[j] = f2bf(sv[j] - bf2f(hh));
        }
        *(s16x8*)&AL[0][nn][h * 8] = shi;
        *(s16x8*)&AL[1][nn][h * 8] = slo;
    }

    float fs[10];
#pragma unroll
    for (int k = 0; k < 10; k++) fs[k] = 0.f;
    float invdeg;
    {
        if (MODE == 1) {
            while (e >= 0) {
                const float4* p = (const float4*)(fr + (size_t)e * 16);
                float4 c2 = p[2];
                float4 c0 = p[0];
                float4 c1 = p[1];
                int en = __float_as_int(c2.y);
                fs[0] += c0.x; fs[1] += c0.y; fs[2] += c0.z; fs[3] += c0.w;
                fs[4] += c1.x; fs[5] += c1.y; fs[6] += c1.z; fs[7] += c1.w;
                fs[8] += c2.x;
                fs[9] += 1.0f;
                e = en;
            }
        } else {
            while (e >= 0) {
                int en = nxt[e];
                const float* f = fr + (size_t)e * 9;
                f4u x = ((const f4u*)f)[0];
                f4u y = ((const f4u*)f)[1];
                float z8 = f[8];
                fs[0] += x.a; fs[1] += x.b; fs[2] += x.c; fs[3] += x.d;
                fs[4] += y.a; fs[5] += y.b; fs[6] += y.c; fs[7] += y.d;
                fs[8] += z8;
                fs[9] += 1.0f;
                e = en;
            }
        }
#pragma unroll
        for (int m = 1; m < 16; m <<= 1) {
#pragma unroll
            for (int k = 0; k < 10; k++) fs[k] += __shfl_xor(fs[k], m);
        }
        invdeg = 1.0f / fmaxf(fs[9], 1.0f);
        if (h < 9) FbarL[nn][h] = fs[h] * invdeg;
    }
    __syncthreads();

    {
        float vh0 = 0.f, vh1 = 0.f, vh2 = 0.f;
#pragma unroll
        for (int i = 0; i < 16; i++) {
            float w = W_vd[i * 16 + h];
            vh0 += vL[nn][i * 3 + 0] * w;
            vh1 += vL[nn][i * 3 + 1] * w;
            vh2 += vL[nn][i * 3 + 2] * w;
        }
        vhL[nn][0][h] = vh0; vhL[nn][1][h] = vh1; vhL[nn][2][h] = vh2;
        float vn = sqrtf(vh0 * vh0 + vh1 * vh1 + vh2 * vh2 + EPSV);
        short hh = f2bf(vn);
        AL[0][nn][128 + h] = hh;
        AL[1][nn][128 + h] = f2bf(vn - bf2f(hh));
        if (h < 9) {
            const int c = h / 3, i = h % 3;
            float a = 0.f;
#pragma unroll
            for (int j = 0; j < 3; j++) {
                float vd = 0.f;
#pragma unroll
                for (int ii = 0; ii < 16; ii++) vd += vL[nn][ii * 3 + j] * W_vdf[ii * 3 + c];
                a += (fs[i * 3 + j] * invdeg) * vd;
            }
            short hs = f2bf(a);
            AL[0][nn][144 + h] = hs;
            AL[1][nn][144 + h] = f2bf(a - bf2f(hs));
        } else {
            AL[0][nn][144 + h] = 0;
            AL[1][nn][144 + h] = 0;
        }
    }
    __syncthreads();

    {
        const int w = t >> 6;
        const int lane = t & 63;
        const int quad = lane >> 4;
        const int col = lane & 15;
        const int o0 = w * 32 + col, o1 = o0 + 16;
        f32x4 acc0 = (f32x4){0.f, 0.f, 0.f, 0.f};
        f32x4 acc1 = (f32x4){0.f, 0.f, 0.f, 0.f};
#pragma unroll
        for (int kk = 0; kk < 5; kk++) {
            const int krow = kk * 32 + quad * 8;
            s16x8 ahi = *(const s16x8*)&AL[0][col][krow];
            s16x8 alo = *(const s16x8*)&AL[1][col][krow];
            s16x8 b0h = *(const s16x8*)&WThi[o0 * 160 + krow];
            s16x8 b0l = *(const s16x8*)&WTlo[o0 * 160 + krow];
            s16x8 b1h = *(const s16x8*)&WThi[o1 * 160 + krow];
            s16x8 b1l = *(const s16x8*)&WTlo[o1 * 160 + krow];
            acc0 = __builtin_amdgcn_mfma_f32_16x16x32_bf16(ahi, b0h, acc0, 0, 0, 0);
            acc0 = __builtin_amdgcn_mfma_f32_16x16x32_bf16(ahi, b0l, acc0, 0, 0, 0);
            acc0 = __builtin_amdgcn_mfma_f32_16x16x32_bf16(alo, b0h, acc0, 0, 0, 0);
            acc1 = __builtin_amdgcn_mfma_f32_16x16x32_bf16(ahi, b1h, acc1, 0, 0, 0);
            acc1 = __builtin_amdgcn_mfma_f32_16x16x32_bf16(ahi, b1l, acc1, 0, 0, 0);
            acc1 = __builtin_amdgcn_mfma_f32_16x16x32_bf16(alo, b1h, acc1, 0, 0, 0);
        }
        __syncthreads();
        {
            float b0 = b_so[o0], b1 = b_so[o1];
#pragma unroll
            for (int r = 0; r < 4; r++) {
                int nl = quad * 4 + r;
                float v0 = acc0[r] + b0;
                float v1 = acc1[r] + b1;
                out0[(size_t)(base + nl) * 128 + o0] = fmaxf(v0, 0.0f);
                out0[(size_t)(base + nl) * 128 + o1] = fmaxf(v1, 0.0f);
                sigL[nl][o0] = sigmoidf_(v0);
                sigL[nl][o1] = sigmoidf_(v1);
            }
        }
    }
    __syncthreads();

    {
        const float* sp = &sigL[nn][h * 8];
        float4 s0 = *(const float4*)sp;
        float4 s1 = *(const float4*)(sp + 4);
        float sv[8] = {s0.x, s0.y, s0.z, s0.w, s1.x, s1.y, s1.z, s1.w};
        float p[9];
#pragma unroll
        for (int k = 0; k < 9; k++) p[k] = 0.f;
#pragma unroll
        for (int i = 0; i < 8; i++) {
            int o = h * 8 + i;
#pragma unroll
            for (int k = 0; k < 9; k++) p[k] += sv[i] * W_vosf[o * 9 + k];
        }
#pragma unroll
        for (int m = 1; m < 16; m <<= 1) {
#pragma unroll
            for (int k = 0; k < 9; k++) p[k] += __shfl_xor(p[k], m);
        }
        if (h < 9) gateL[nn][h] = p[h] + b_vosf[h];
    }
    __syncthreads();

    {
        int o = h;
        float gv[9];
#pragma unroll
        for (int i = 0; i < 3; i++)
#pragma unroll
            for (int kk = 0; kk < 3; kk++) {
                float a = 0.f;
#pragma unroll
                for (int j = 0; j < 3; j++) a += gateL[nn][j * 3 + i] * FbarL[nn][j * 3 + kk];
                gv[i * 3 + kk] = a;
            }
        float gvr[3];
#pragma unroll
        for (int kk = 0; kk < 3; kk++) {
            float a = 0.f;
#pragma unroll
            for (int i = 0; i < 3; i++) a += gv[i * 3 + kk] * W_vuf[i * 16 + o];
            gvr[kk] = a;
        }
        float gn2 = sqrtf(gvr[0] * gvr[0] + gvr[1] * gvr[1] + gvr[2] * gvr[2] + EPSV);
        float sg = sigmoidf_(gn2);
#pragma unroll
        for (int c = 0; c < 3; c++) {
            float a = 0.f;
#pragma unroll
            for (int h2 = 0; h2 < 16; h2++) a += vhL[nn][c][h2] * W_vu[h2 * 16 + o];
            out1[(size_t)n * 48 + o * 3 + c] = a * sg;
        }
    }
}

extern "C" void kernel_launch(void* const* d_in, const int* in_sizes, int n_in,
                              void* d_out, int out_size, void* d_ws, size_t ws_size,
                              hipStream_t stream) {
    const float* s      = (const float*)d_in[0];
    const float* v      = (const float*)d_in[1];
    const float* frames = (const float*)d_in[2];
    const float* W_vd   = (const float*)d_in[3];
    const float* W_vdf  = (const float*)d_in[4];
    const float* W_so   = (const float*)d_in[5];
    const float* b_so   = (const float*)d_in[6];
    const float* W_vu   = (const float*)d_in[7];
    const float* W_vosf = (const float*)d_in[8];
    const float* b_vosf = (const float*)d_in[9];
    const float* W_vuf  = (const float*)d_in[10];
    const int* edge_index = (const int*)d_in[11];
    // d_in[12] = node_inputs (assumed truthy, per reference)

    float* out0 = (float*)d_out;
    float* out1 = out0 + (size_t)N_NODES * 128;

    const size_t wt_b    = (size_t)128 * 160 * sizeof(short);        // 40,960
    // BIN layout: bincnt[3136] | head2[50K*16] | WThi | WTlo | nxt[E] | pay48[3125*cap*48B]
    const size_t bcnt_b  = (size_t)3136 * sizeof(int);               // 12,544
    const size_t head2_b = (size_t)N_NODES * NCHAIN * sizeof(int);   // 3,200,000
    const size_t nxt_b   = (size_t)N_EDGES * sizeof(int);            // 6,400,000
    const size_t bin_base = bcnt_b + head2_b + 2 * wt_b + nxt_b;     // 9,694,464
    long capB = 0;
    if (ws_size > bin_base)
        capB = (long)((ws_size - bin_base) / ((size_t)NBINS * 48));
    if (capB > 1024) capB = 1024;

    // FAT layout: head[50K*16] | WThi | WTlo | pay64[E*64B]
    const size_t head_b  = (size_t)N_NODES * NCHAIN * sizeof(int);
    const size_t fat_off = head_b + 2 * wt_b;
    const size_t fat_need = fat_off + (size_t)N_EDGES * 64;

    if (capB >= 560) {
        // ---- BIN path ----
        int*   bcnt  = (int*)d_ws;
        int*   head2 = (int*)((char*)d_ws + bcnt_b);
        short* WThi  = (short*)((char*)d_ws + bcnt_b + head2_b);
        short* WTlo  = WThi + 128 * 160;
        int*   nxt   = (int*)((char*)d_ws + bcnt_b + head2_b + 2 * wt_b);
        float* pay   = (float*)((char*)d_ws + bin_base);
        init_kernel<<<(N_NODES * NCHAIN + 255) / 256, 256, 0, stream>>>(
            W_so, WThi, WTlo, bcnt, head2, 3);
        bucket_bin_kernel<<<(N_EDGES + 255) / 256, 256, 0, stream>>>(
            edge_index, frames, bcnt, head2, nxt, pay, (int)capB);
        node_bin_kernel<<<NBINS, 256, 0, stream>>>(
            s, v, pay, frames, W_vd, W_vdf, WThi, WTlo, b_so, W_vu, W_vosf, b_vosf, W_vuf,
            bcnt, head2, nxt, (int)capB, out0, out1);
    } else if (ws_size >= fat_need) {
        // ---- FAT chain path ----
        int*   head = (int*)d_ws;
        short* WThi = (short*)((char*)d_ws + head_b);
        short* WTlo = WThi + 128 * 160;
        float* pay  = (float*)((char*)d_ws + fat_off);
        init_kernel<<<(N_NODES * NCHAIN + 255) / 256, 256, 0, stream>>>(
            W_so, WThi, WTlo, head, (int*)nullptr, 1);
        bucket_fat_kernel<<<(N_EDGES + 255) / 256, 256, 0, stream>>>(
            edge_index, frames, head, pay);
        node_kernel<1><<<N_NODES / NPB, 256, 0, stream>>>(
            s, v, pay, W_vd, W_vdf, WThi, WTlo, b_so, W_vu, W_vosf, b_vosf, W_vuf,
            head, (const int*)nullptr, out0, out1);
    } else {
        // ---- thin path ----
        int*   head = (int*)d_ws;
        short* WThi = (short*)((char*)d_ws + head_b);
        short* WTlo = WThi + 128 * 160;
        int*   nxt  = (int*)((char*)d_ws + fat_off);
        init_kernel<<<(N_NODES * NCHAIN + 255) / 256, 256, 0, stream>>>(
            W_so, WThi, WTlo, head, (int*)nullptr, 0);
        bucket_thin_kernel<<<(N_EDGES + 255) / 256, 256, 0, stream>>>(
            edge_index, head, nxt);
        node_kernel<0><<<N_NODES / NPB, 256, 0, stream>>>(
            s, v, frames, W_vd, W_vdf, WThi, WTlo, b_so, W_vu, W_vosf, b_vosf, W_vuf,
            head, nxt, out0, out1);
    }
}

// Round 9
// 267.994 us; speedup vs baseline: 1.4791x; 1.4791x over previous
//
#include <hip/hip_runtime.h>

#define N_NODES 50000
#define N_EDGES 1600000
#define NPB     16
#define NCHAIN  16    // fat/thin sub-chains per node: chain = e & 15
#define KSTR    168   // A-tile k-stride in shorts (160 + 8 pad: breaks bank conflict on A-frag ds_read_b128)
#define EPSV    1e-8f

typedef float f32x4 __attribute__((ext_vector_type(4)));
typedef short s16x8 __attribute__((ext_vector_type(8)));

// 4-aligned 16B chunk (frames rows are 36B, only 4B-aligned)
struct f4u { float a, b, c, d; };

__device__ __forceinline__ float sigmoidf_(float x) { return 1.0f / (1.0f + __expf(-x)); }
// f32 -> bf16 bits, round-to-nearest-even
__device__ __forceinline__ short f2bf(float x) {
    unsigned u = __float_as_uint(x);
    unsigned r = (u + 0x7FFFu + ((u >> 16) & 1u)) >> 16;
    return (short)r;
}
__device__ __forceinline__ float bf2f(short h) {
    return __uint_as_float(((unsigned)(unsigned short)h) << 16);
}
// pack two f32 -> one u32 of 2 bf16 (lo = first)
__device__ __forceinline__ unsigned pkbf(float lo, float hi) {
    return (unsigned)(unsigned short)f2bf(lo) | ((unsigned)(unsigned short)f2bf(hi) << 16);
}
__device__ __forceinline__ float bflo(unsigned u) { return __uint_as_float(u << 16); }
__device__ __forceinline__ float bfhi(unsigned u) { return __uint_as_float(u & 0xffff0000u); }

// ---------------------------------------------------------------------------
// Init kernel: head[] = -1  AND  Dekker-split W_so into TRANSPOSED bf16 hi/lo
// WT[o][k] (k-contiguous so each MFMA B-frag is one 16B load), k>=153 zeroed.
// ---------------------------------------------------------------------------
__global__ __launch_bounds__(256) void init_kernel(
    const float* __restrict__ W_so, short* __restrict__ WThi, short* __restrict__ WTlo,
    int* __restrict__ head) {
    int i = blockIdx.x * 256 + threadIdx.x;
    if (i < 128 * 160) {               // i = o*160 + k
        int o = i / 160, k = i - o * 160;
        float w = (k < 153) ? W_so[k * 128 + o] : 0.0f;
        short hh = f2bf(w);
        WThi[i] = hh;
        WTlo[i] = f2bf(w - bf2f(hh));
    }
    if (i < N_NODES * NCHAIN) head[i] = -1;
}

// ---------------------------------------------------------------------------
// Kernel 1 (FAT-bf16): 16-way bucketing fused with COMPRESSED payload
// scatter. Per edge: 1 atomicExch (800K addresses — r6/r7/r8 proved atomic
// cost rises monotonically as addresses shrink: 800K<=85us, 50K=116, 3125=155)
// + coalesced frame read + ONE fully-written 32B sector:
//   w0..w3 = f0..f7 as bf16 pairs, w4 = {f8, 0}, w5 = nxt, w6..w7 = 0.
// Sector-aligned + fully written -> no partial-sector RMW, no cross-XCD
// line sharing (each slot owns its sector). Payload 102.4 -> 51.2 MB.
// bf16 frames are safe: downstream error ~3e-4 on out0 vs 2^-7 threshold.
// ---------------------------------------------------------------------------
__global__ __launch_bounds__(256) void bucket_fat_kernel(
    const int* __restrict__ row,
    const float* __restrict__ frames,
    int* __restrict__ head,
    unsigned* __restrict__ pay) {
    int e = blockIdx.x * 256 + threadIdx.x;
    if (e >= N_EDGES) return;
    int r = row[e];
    int prev = atomicExch(&head[r * NCHAIN + (e & (NCHAIN - 1))], e);
    const float* f = frames + (size_t)e * 9;
    f4u x = ((const f4u*)f)[0];
    f4u y = ((const f4u*)f)[1];
    float z8 = f[8];
    uint4* dst = (uint4*)(pay + (size_t)e * 8);
    dst[0] = make_uint4(pkbf(x.a, x.b), pkbf(x.c, x.d), pkbf(y.a, y.b), pkbf(y.c, y.d));
    dst[1] = make_uint4((unsigned)(unsigned short)f2bf(z8), (unsigned)prev, 0u, 0u);
}

// Thin fallback (tiny ws): classic separate-nxt bucketing.
__global__ __launch_bounds__(256) void bucket_thin_kernel(
    const int* __restrict__ row,
    int* __restrict__ head,
    int* __restrict__ nxt) {
    int e = blockIdx.x * 256 + threadIdx.x;
    if (e >= N_EDGES) return;
    int r = row[e];
    int prev = atomicExch(&head[r * NCHAIN + (e & (NCHAIN - 1))], e);
    nxt[e] = prev;
}

// ---------------------------------------------------------------------------
// Kernel 2: all per-node algebra. 16 nodes per 256-thread block.
// MODE 1 (fat-bf16): walker reads ONE 32B sector per hop (2 loads: frame
//   bf16s + nxt together); decode = 9 shifts.
// MODE 0 (thin): nxt array + raw f32 frames.
// Default launch bounds: (256,8) clamp spilled twice (r2 +47MB, r4 +15MB
// writes); occupancy is not the lever for this kernel (39% vs 74% equal).
// ---------------------------------------------------------------------------
template<int MODE>
__global__ __launch_bounds__(256) void node_kernel(
    const float* __restrict__ s,
    const float* __restrict__ v,
    const unsigned* __restrict__ pay,  // MODE 1 only
    const float* __restrict__ frames,  // MODE 0 only
    const float* __restrict__ W_vd,
    const float* __restrict__ W_vdf,
    const short* __restrict__ WThi,
    const short* __restrict__ WTlo,
    const float* __restrict__ b_so,
    const float* __restrict__ W_vu,
    const float* __restrict__ W_vosf,
    const float* __restrict__ b_vosf,
    const float* __restrict__ W_vuf,
    const int* __restrict__ head,
    const int* __restrict__ nxt,       // MODE 0 only
    float* __restrict__ out0,
    float* __restrict__ out1)
{
    // AL[0]=A hi, AL[1]=A lo, rows k-strided by KSTR shorts. 10.5 KB.
    // After the K-loop barrier it is dead and sigL[16][128] (8 KB) overlays it.
    __shared__ __align__(16) short AL[2][NPB][KSTR];
    __shared__ float vL[NPB][48];
    __shared__ float vhL[NPB][3][16];
    __shared__ float FbarL[NPB][9];
    __shared__ float gateL[NPB][12];

    float (*sigL)[128] = (float (*)[128])&AL[0][0][0];

    const int t = threadIdx.x;
    const int base = blockIdx.x * NPB;
    const int nn = t >> 4, h = t & 15;
    const int n = base + nn;

    // ---- phase 0: issue head load first (latency overlaps staging), stage
    //      v, s(->bf16 hi/lo); 256 walkers traverse the 16 sub-chains ----
    int e = head[(size_t)n * NCHAIN + h];

#pragma unroll
    for (int r = 0; r < 3; r++) vL[nn][h * 3 + r] = v[(size_t)n * 48 + h * 3 + r];
    {
        const float4* sp4 = (const float4*)(s + (size_t)n * 128 + h * 8);
        float4 s0 = sp4[0], s1 = sp4[1];
        float sv[8] = {s0.x, s0.y, s0.z, s0.w, s1.x, s1.y, s1.z, s1.w};
        s16x8 shi, slo;
#pragma unroll
        for (int j = 0; j < 8; j++) {
            short hh = f2bf(sv[j]);
            shi[j] = hh;
            slo[j] = f2bf(sv[j] - bf2f(hh));
        }
        *(s16x8*)&AL[0][nn][h * 8] = shi;
        *(s16x8*)&AL[1][nn][h * 8] = slo;
    }

    float fs[10];   // after butterfly: ALL lanes hold the node's full sums
#pragma unroll
    for (int k = 0; k < 10; k++) fs[k] = 0.f;
    float invdeg;
    {
        if (MODE == 1) {
            while (e >= 0) {
                const uint4* p = (const uint4*)(pay + (size_t)e * 8);
                uint4 b = p[1];                 // {f8, nxt, 0, 0} - same sector
                uint4 a = p[0];
                int en = (int)b.y;
                fs[0] += bflo(a.x); fs[1] += bfhi(a.x);
                fs[2] += bflo(a.y); fs[3] += bfhi(a.y);
                fs[4] += bflo(a.z); fs[5] += bfhi(a.z);
                fs[6] += bflo(a.w); fs[7] += bfhi(a.w);
                fs[8] += bflo(b.x);
                fs[9] += 1.0f;
                e = en;
            }
        } else {
            while (e >= 0) {
                int en = nxt[e];
                const float* f = frames + (size_t)e * 9;
                f4u x = ((const f4u*)f)[0];
                f4u y = ((const f4u*)f)[1];
                float z8 = f[8];
                fs[0] += x.a; fs[1] += x.b; fs[2] += x.c; fs[3] += x.d;
                fs[4] += y.a; fs[5] += y.b; fs[6] += y.c; fs[7] += y.d;
                fs[8] += z8;
                fs[9] += 1.0f;
                e = en;
            }
        }
        // butterfly across the node's 16 lanes (contiguous within the wave)
#pragma unroll
        for (int m = 1; m < 16; m <<= 1) {
#pragma unroll
            for (int k = 0; k < 10; k++) fs[k] += __shfl_xor(fs[k], m);
        }
        invdeg = 1.0f / fmaxf(fs[9], 1.0f);
        if (h < 9) FbarL[nn][h] = fs[h] * invdeg;   // for phase 3
    }
    __syncthreads();

    // ---- phase 1 (fused): vh, vnorm(->A[128+h]), sh(->A[144..152]) ----
    {
        float vh0 = 0.f, vh1 = 0.f, vh2 = 0.f;
#pragma unroll
        for (int i = 0; i < 16; i++) {
            float w = W_vd[i * 16 + h];
            vh0 += vL[nn][i * 3 + 0] * w;
            vh1 += vL[nn][i * 3 + 1] * w;
            vh2 += vL[nn][i * 3 + 2] * w;
        }
        vhL[nn][0][h] = vh0; vhL[nn][1][h] = vh1; vhL[nn][2][h] = vh2;
        float vn = sqrtf(vh0 * vh0 + vh1 * vh1 + vh2 * vh2 + EPSV);
        short hh = f2bf(vn);
        AL[0][nn][128 + h] = hh;
        AL[1][nn][128 + h] = f2bf(vn - bf2f(hh));
        if (h < 9) {
            // sh[h]: c = h/3 (vdf column), i = h%3 (Fbar row)
            const int c = h / 3, i = h % 3;
            float a = 0.f;
#pragma unroll
            for (int j = 0; j < 3; j++) {
                // vdf[j*3+c] recomputed in-lane (3 dots of 16, vL same-group)
                float vd = 0.f;
#pragma unroll
                for (int ii = 0; ii < 16; ii++) vd += vL[nn][ii * 3 + j] * W_vdf[ii * 3 + c];
                a += (fs[i * 3 + j] * invdeg) * vd;   // Fbar from registers
            }
            short hs = f2bf(a);
            AL[0][nn][144 + h] = hs;
            AL[1][nn][144 + h] = f2bf(a - bf2f(hs));
        } else {
            AL[0][nn][144 + h] = 0;  // k = 153..159
            AL[1][nn][144 + h] = 0;
        }
    }
    __syncthreads();

    // ---- phase 2: C[16x128] = merged[16x160] @ W_so via split-bf16 MFMA ----
    // wave w handles o in [32w, 32w+32): two 16x16 tiles, K-loop 5x32.
    // A-frag: A[m=lane&15][k=quad*8+j] (ds_read_b128 from AL);
    // B-frag: B[k=quad*8+j][n=lane&15] (one b128 from WT[o][k] each);
    // C/D: col=lane&15, row=quad*4+reg (m89/m91/m120-verified layouts).
    {
        const int w = t >> 6;
        const int lane = t & 63;
        const int quad = lane >> 4;
        const int col = lane & 15;
        const int o0 = w * 32 + col, o1 = o0 + 16;
        f32x4 acc0 = (f32x4){0.f, 0.f, 0.f, 0.f};
        f32x4 acc1 = (f32x4){0.f, 0.f, 0.f, 0.f};
#pragma unroll
        for (int kk = 0; kk < 5; kk++) {
            const int krow = kk * 32 + quad * 8;
            s16x8 ahi = *(const s16x8*)&AL[0][col][krow];
            s16x8 alo = *(const s16x8*)&AL[1][col][krow];
            s16x8 b0h = *(const s16x8*)&WThi[o0 * 160 + krow];
            s16x8 b0l = *(const s16x8*)&WTlo[o0 * 160 + krow];
            s16x8 b1h = *(const s16x8*)&WThi[o1 * 160 + krow];
            s16x8 b1l = *(const s16x8*)&WTlo[o1 * 160 + krow];
            acc0 = __builtin_amdgcn_mfma_f32_16x16x32_bf16(ahi, b0h, acc0, 0, 0, 0);
            acc0 = __builtin_amdgcn_mfma_f32_16x16x32_bf16(ahi, b0l, acc0, 0, 0, 0);
            acc0 = __builtin_amdgcn_mfma_f32_16x16x32_bf16(alo, b0h, acc0, 0, 0, 0);
            acc1 = __builtin_amdgcn_mfma_f32_16x16x32_bf16(ahi, b1h, acc1, 0, 0, 0);
            acc1 = __builtin_amdgcn_mfma_f32_16x16x32_bf16(ahi, b1l, acc1, 0, 0, 0);
            acc1 = __builtin_amdgcn_mfma_f32_16x16x32_bf16(alo, b1h, acc1, 0, 0, 0);
        }
        __syncthreads();  // all A-frag reads of AL done -> safe to overlay sigL
        // epilogue: bias, relu -> out0, sigmoid -> sigL (overlaid on AL)
        {
            float b0 = b_so[o0], b1 = b_so[o1];
#pragma unroll
            for (int r = 0; r < 4; r++) {
                int nl = quad * 4 + r;
                float v0 = acc0[r] + b0;
                float v1 = acc1[r] + b1;
                out0[(size_t)(base + nl) * 128 + o0] = fmaxf(v0, 0.0f);
                out0[(size_t)(base + nl) * 128 + o1] = fmaxf(v1, 0.0f);
                sigL[nl][o0] = sigmoidf_(v0);
                sigL[nl][o1] = sigmoidf_(v1);
            }
        }
    }
    __syncthreads();

    // ---- gate = sigmoid(sr) @ W_vosf + b_vosf : partials + shfl butterfly ----
    {
        const float* sp = &sigL[nn][h * 8];
        float4 s0 = *(const float4*)sp;
        float4 s1 = *(const float4*)(sp + 4);
        float sv[8] = {s0.x, s0.y, s0.z, s0.w, s1.x, s1.y, s1.z, s1.w};
        float p[9];
#pragma unroll
        for (int k = 0; k < 9; k++) p[k] = 0.f;
#pragma unroll
        for (int i = 0; i < 8; i++) {
            int o = h * 8 + i;
#pragma unroll
            for (int k = 0; k < 9; k++) p[k] += sv[i] * W_vosf[o * 9 + k];
        }
#pragma unroll
        for (int m = 1; m < 16; m <<= 1) {
#pragma unroll
            for (int k = 0; k < 9; k++) p[k] += __shfl_xor(p[k], m);
        }
        if (h < 9) gateL[nn][h] = p[h] + b_vosf[h];
    }
    __syncthreads();

    // ---- phase 3: vector path ----
    {
        int o = h;  // VO index
        float gv[9];
#pragma unroll
        for (int i = 0; i < 3; i++)
#pragma unroll
            for (int kk = 0; kk < 3; kk++) {
                float a = 0.f;
#pragma unroll
                for (int j = 0; j < 3; j++) a += gateL[nn][j * 3 + i] * FbarL[nn][j * 3 + kk];
                gv[i * 3 + kk] = a;
            }
        float gvr[3];
#pragma unroll
        for (int kk = 0; kk < 3; kk++) {
            float a = 0.f;
#pragma unroll
            for (int i = 0; i < 3; i++) a += gv[i * 3 + kk] * W_vuf[i * 16 + o];
            gvr[kk] = a;
        }
        float gn2 = sqrtf(gvr[0] * gvr[0] + gvr[1] * gvr[1] + gvr[2] * gvr[2] + EPSV);
        float sg = sigmoidf_(gn2);
#pragma unroll
        for (int c = 0; c < 3; c++) {
            float a = 0.f;
#pragma unroll
            for (int h2 = 0; h2 < 16; h2++) a += vhL[nn][c][h2] * W_vu[h2 * 16 + o];
            out1[(size_t)n * 48 + o * 3 + c] = a * sg;
        }
    }
}

extern "C" void kernel_launch(void* const* d_in, const int* in_sizes, int n_in,
                              void* d_out, int out_size, void* d_ws, size_t ws_size,
                              hipStream_t stream) {
    const float* s      = (const float*)d_in[0];
    const float* v      = (const float*)d_in[1];
    const float* frames = (const float*)d_in[2];
    const float* W_vd   = (const float*)d_in[3];
    const float* W_vdf  = (const float*)d_in[4];
    const float* W_so   = (const float*)d_in[5];
    const float* b_so   = (const float*)d_in[6];
    const float* W_vu   = (const float*)d_in[7];
    const float* W_vosf = (const float*)d_in[8];
    const float* b_vosf = (const float*)d_in[9];
    const float* W_vuf  = (const float*)d_in[10];
    const int* edge_index = (const int*)d_in[11];
    // d_in[12] = node_inputs (assumed truthy, per reference)

    // ws layout: head[50K*16 int] | WThi | WTlo | payload
    //   payload (fat-bf16): pay[E * 32B sectors]  (51.2 MB)
    //   payload (thin):     nxt[E int]            (6.4 MB)
    const size_t head_b = (size_t)N_NODES * NCHAIN * sizeof(int);  // 3,200,000
    const size_t wt_b   = (size_t)128 * 160 * sizeof(short);       // 40,960
    const size_t pay_off = head_b + 2 * wt_b;                      // 3,281,920 (32B mult)
    int*   head = (int*)d_ws;
    short* WThi = (short*)((char*)d_ws + head_b);
    short* WTlo = WThi + 128 * 160;
    float* out0 = (float*)d_out;
    float* out1 = out0 + (size_t)N_NODES * 128;

    const size_t fat_need = pay_off + (size_t)N_EDGES * 32;
    init_kernel<<<(N_NODES * NCHAIN + 255) / 256, 256, 0, stream>>>(W_so, WThi, WTlo, head);

    if (ws_size >= fat_need) {
        unsigned* pay = (unsigned*)((char*)d_ws + pay_off);
        bucket_fat_kernel<<<(N_EDGES + 255) / 256, 256, 0, stream>>>(edge_index, frames, head, pay);
        node_kernel<1><<<N_NODES / NPB, 256, 0, stream>>>(
            s, v, pay, frames, W_vd, W_vdf, WThi, WTlo, b_so, W_vu, W_vosf, b_vosf, W_vuf,
            head, (const int*)nullptr, out0, out1);
    } else {
        int* nxt = (int*)((char*)d_ws + pay_off);
        bucket_thin_kernel<<<(N_EDGES + 255) / 256, 256, 0, stream>>>(edge_index, head, nxt);
        node_kernel<0><<<N_NODES / NPB, 256, 0, stream>>>(
            s, v, (const unsigned*)nullptr, frames, W_vd, W_vdf, WThi, WTlo, b_so, W_vu, W_vosf, b_vosf, W_vuf,
            head, nxt, out0, out1);
    }
}